// Round 2
// baseline (429.649 us; speedup 1.0000x reference)
//
#include <hip/hip_runtime.h>
#include <hip/hip_bf16.h>

// ---------------------------------------------------------------------------
// BasicTransformerBlock (l2-attention x2 + GEGLU FFN), MI355X gfx950
// Round 12: attention was grid-capped at 4 blocks/CU (occupancy 34.5%, both
// pipes <50% -> latency-bound). Split the KV range 2-way per block
// (flash-decoding): grid 1024 -> 2048 = 8 blocks/CU = 32 waves/CU, fp32
// O/lr partials into the (FFN-phase-only) gbuf region, plus a 40MB-traffic
// combine pass. Also s_setprio(1) around attn MFMA clusters (T5).
// ---------------------------------------------------------------------------

typedef short bf16x8 __attribute__((ext_vector_type(8)));
typedef float f32x4 __attribute__((ext_vector_type(4)));
typedef unsigned short u16;
typedef unsigned int u32;

__device__ __forceinline__ float bf2f(u16 u) {
    return __uint_as_float(((u32)u) << 16);
}
__device__ __forceinline__ u16 f2bf(float f) {
    u32 u = __float_as_uint(f);
    u32 rb = ((u >> 16) & 1u) + 0x7fffu;   // round-to-nearest-even
    return (u16)((u + rb) >> 16);
}
// tanh-form gelu: x * sigmoid(1.59577(x + 0.044715 x^3)); |err| <~1e-3.
__device__ __forceinline__ float gelu_fast(float x) {
    float y = 1.5957691216f * (x + 0.044715f * x * x * x);
    return x / (1.f + __expf(-y));
}
__device__ __forceinline__ void gl2lds16(const u16* g, u16* l) {
    __builtin_amdgcn_global_load_lds(
        (const __attribute__((address_space(1))) void*)(unsigned long long)(uintptr_t)g,
        (__attribute__((address_space(3))) void*)(unsigned long long)(uintptr_t)l,
        16, 0, 0);
}

// ---------------------------------------------------------------------------
// Merged weight transpose: 8 segments of fp32 [R][C] -> bf16 [C][R].
struct TArgs {
    const float* src[8];
    u16* dst[8];
    int R[8], C[8];
    int start[9];
};
__global__ __launch_bounds__(256) void transpose_multi(TArgs a) {
    __shared__ float tile[32][33];
    int bid = blockIdx.x;
    int s = 0;
    while (bid >= a.start[s + 1]) s++;
    int local = bid - a.start[s];
    int R = a.R[s], C = a.C[s];
    int tx = C >> 5;
    int bx = local % tx, by = local / tx;
    const float* in = a.src[s];
    u16* out = a.dst[s];
    int t = threadIdx.x;
    int c = t & 31, r0 = (t >> 5) * 4;
#pragma unroll
    for (int i = 0; i < 4; i++)
        tile[r0 + i][c] = in[(size_t)(by * 32 + r0 + i) * C + bx * 32 + c];
    __syncthreads();
#pragma unroll
    for (int i = 0; i < 4; i++)
        out[(size_t)(bx * 32 + r0 + i) * R + by * 32 + c] = f2bf(tile[c][r0 + i]);
}

// ---------------------------------------------------------------------------
// LayerNorm: x fp32 [rows][512] -> out bf16, one block per row
__global__ __launch_bounds__(256) void ln_kernel(const float* __restrict__ x,
                                                 const float* __restrict__ w,
                                                 const float* __restrict__ b,
                                                 u16* __restrict__ out) {
    int row = blockIdx.x, t = threadIdx.x;
    const float* xr = x + (size_t)row * 512;
    float2 v = *(const float2*)(xr + t * 2);
    float s1 = v.x + v.y;
    float s2 = v.x * v.x + v.y * v.y;
#pragma unroll
    for (int m = 1; m < 64; m <<= 1) {
        s1 += __shfl_xor(s1, m);
        s2 += __shfl_xor(s2, m);
    }
    __shared__ float r1[4], r2[4];
    int wave = t >> 6, lane = t & 63;
    if (lane == 0) { r1[wave] = s1; r2[wave] = s2; }
    __syncthreads();
    float tot1 = r1[0] + r1[1] + r1[2] + r1[3];
    float tot2 = r2[0] + r2[1] + r2[2] + r2[3];
    float mu = tot1 * (1.f / 512.f);
    float var = tot2 * (1.f / 512.f) - mu * mu;
    float rs = rsqrtf(var + 1e-5f);
    float2 wv = *(const float2*)(w + t * 2);
    float2 bv = *(const float2*)(b + t * 2);
    float o0 = (v.x - mu) * rs * wv.x + bv.x;
    float o1 = (v.y - mu) * rs * wv.y + bv.y;
    u32 pack = (u32)f2bf(o0) | ((u32)f2bf(o1) << 16);
    *(u32*)(out + (size_t)row * 512 + t * 2) = pack;
}

// ---------------------------------------------------------------------------
// ff1+GEGLU fused rect GEMM: A [8192][512] bf16, BT = ff1^T [4096][512].
// Epilogue: g = a * gelu(gate) -> gbuf [8192][2048] bf16.
__global__ __launch_bounds__(256) void gemm_ff1(const u16* __restrict__ A,
                                                const u16* __restrict__ BT,
                                                const float* __restrict__ bias,
                                                u16* __restrict__ gout,
                                                int K) {
    __shared__ u16 As[2][128 * 32];
    __shared__ u16 Bs[2][128 * 32];   // rows 0-63 = a-half, 64-127 = gate-half
    int t = threadIdx.x;
    int wave = t >> 6, lane = t & 63, quad = lane >> 4, l16 = lane & 15;
    int m0 = blockIdx.x * 128, n0 = blockIdx.y * 64;
    f32x4 aacc[2][4], gacc[2][4];
#pragma unroll
    for (int i = 0; i < 2; i++)
#pragma unroll
        for (int j = 0; j < 4; j++) {
            aacc[i][j] = (f32x4){0.f, 0.f, 0.f, 0.f};
            gacc[i][j] = (f32x4){0.f, 0.f, 0.f, 0.f};
        }
    const u16* Ag = A + (size_t)(m0 + wave * 32 + (lane >> 2)) * K + (lane & 3) * 8;
    int brow = (wave < 2) ? (n0 + wave * 32) : (2048 + n0 + (wave - 2) * 32);
    const u16* Bg = BT + (size_t)(brow + (lane >> 2)) * K + (lane & 3) * 8;
    int lo = wave * 32 * 32;
    const size_t rstep = (size_t)16 * K;
    gl2lds16(Ag, &As[0][lo]);
    gl2lds16(Ag + rstep, &As[0][lo + 16 * 32]);
    gl2lds16(Bg, &Bs[0][lo]);
    gl2lds16(Bg + rstep, &Bs[0][lo + 16 * 32]);
    int buf = 0;
    for (int k0 = 0; k0 < K; k0 += 32, buf ^= 1) {
        int kn = (k0 + 32 < K) ? (k0 + 32) : k0;
        int nb = buf ^ 1;
        asm volatile("s_waitcnt lgkmcnt(0)\n\ts_barrier" ::: "memory");
        gl2lds16(Ag + kn, &As[nb][lo]);
        gl2lds16(Ag + kn + rstep, &As[nb][lo + 16 * 32]);
        gl2lds16(Bg + kn, &Bs[nb][lo]);
        gl2lds16(Bg + kn + rstep, &Bs[nb][lo + 16 * 32]);
        asm volatile("s_waitcnt vmcnt(4)\n\ts_barrier" ::: "memory");
        bf16x8 a[2];
#pragma unroll
        for (int i = 0; i < 2; i++)
            a[i] = *(const bf16x8*)&As[buf][(wave * 32 + i * 16 + l16) * 32 + quad * 8];
#pragma unroll
        for (int j = 0; j < 4; j++) {
            bf16x8 ba = *(const bf16x8*)&Bs[buf][(j * 16 + l16) * 32 + quad * 8];
            bf16x8 bg = *(const bf16x8*)&Bs[buf][(64 + j * 16 + l16) * 32 + quad * 8];
#pragma unroll
            for (int i = 0; i < 2; i++) {
                aacc[i][j] = __builtin_amdgcn_mfma_f32_16x16x32_bf16(a[i], ba, aacc[i][j], 0, 0, 0);
                gacc[i][j] = __builtin_amdgcn_mfma_f32_16x16x32_bf16(a[i], bg, gacc[i][j], 0, 0, 0);
            }
        }
    }
    asm volatile("s_waitcnt vmcnt(0)" ::: "memory");   // drain DMA before endpgm
    int row_base = m0 + wave * 32 + quad * 4;
#pragma unroll
    for (int j = 0; j < 4; j++) {
        int col = n0 + j * 16 + l16;
        float ba = bias[col];
        float bg = bias[2048 + col];
#pragma unroll
        for (int i = 0; i < 2; i++) {
#pragma unroll
            for (int r = 0; r < 4; r++) {
                int row = row_base + i * 16 + r;
                float av = aacc[i][j][r] + ba;
                float gv = gacc[i][j][r] + bg;
                gout[(size_t)row * 2048 + col] = f2bf(av * gelu_fast(gv));
            }
        }
    }
}

// ---------------------------------------------------------------------------
// Rect 128x64 MFMA GEMM (double-buffered, vmcnt(3)).
// MODE 2: fp32 out = acc + res | 4: qv split:
//   col<512 (q): qbuf [(b*8+h)][n][64] + fused AA write (aa = 0.125*sum q^2)
//   col>=512 (v): vtp [(b*8+h)][64][2048] j-cols PERMUTED per aligned 32-block
template <int MODE>
__global__ __launch_bounds__(256) void gemm_rect(const u16* __restrict__ A,
                                                 const u16* __restrict__ BT,
                                                 const float* __restrict__ bias,
                                                 const float* __restrict__ bias2,
                                                 const float* __restrict__ res,
                                                 float* __restrict__ outf,
                                                 u16* __restrict__ outb,
                                                 u16* __restrict__ outb2,
                                                 float* __restrict__ aa,
                                                 int M, int N, int K) {
    __shared__ u16 As[2][128 * 32];
    __shared__ u16 Bs[2][64 * 32];
    int t = threadIdx.x;
    int wave = t >> 6, lane = t & 63, quad = lane >> 4, l16 = lane & 15;
    int m0 = blockIdx.x * 128, n0 = blockIdx.y * 64;
    f32x4 acc[2][4];
#pragma unroll
    for (int i = 0; i < 2; i++)
#pragma unroll
        for (int j = 0; j < 4; j++) acc[i][j] = (f32x4){0.f, 0.f, 0.f, 0.f};
    const u16* Ag = A + (size_t)(m0 + wave * 32 + (lane >> 2)) * K + (lane & 3) * 8;
    const u16* Bg = BT + (size_t)(n0 + wave * 16 + (lane >> 2)) * K + (lane & 3) * 8;
    int loA = wave * 32 * 32;
    int loB = wave * 16 * 32;
    const size_t rstep = (size_t)16 * K;
    gl2lds16(Ag, &As[0][loA]);
    gl2lds16(Ag + rstep, &As[0][loA + 16 * 32]);
    gl2lds16(Bg, &Bs[0][loB]);
    int buf = 0;
    for (int k0 = 0; k0 < K; k0 += 32, buf ^= 1) {
        int kn = (k0 + 32 < K) ? (k0 + 32) : k0;
        int nb = buf ^ 1;
        asm volatile("s_waitcnt lgkmcnt(0)\n\ts_barrier" ::: "memory");
        gl2lds16(Ag + kn, &As[nb][loA]);
        gl2lds16(Ag + kn + rstep, &As[nb][loA + 16 * 32]);
        gl2lds16(Bg + kn, &Bs[nb][loB]);
        asm volatile("s_waitcnt vmcnt(3)\n\ts_barrier" ::: "memory");
        bf16x8 a[2], b[4];
#pragma unroll
        for (int i = 0; i < 2; i++)
            a[i] = *(const bf16x8*)&As[buf][(wave * 32 + i * 16 + l16) * 32 + quad * 8];
#pragma unroll
        for (int j = 0; j < 4; j++)
            b[j] = *(const bf16x8*)&Bs[buf][(j * 16 + l16) * 32 + quad * 8];
#pragma unroll
        for (int i = 0; i < 2; i++)
#pragma unroll
            for (int j = 0; j < 4; j++)
                acc[i][j] = __builtin_amdgcn_mfma_f32_16x16x32_bf16(a[i], b[j], acc[i][j], 0, 0, 0);
    }
    asm volatile("s_waitcnt vmcnt(0)" ::: "memory");   // drain DMA before endpgm
    int row_base = m0 + wave * 32 + quad * 4;
    float ssq[2][4];
#pragma unroll
    for (int i = 0; i < 2; i++)
#pragma unroll
        for (int r = 0; r < 4; r++) ssq[i][r] = 0.f;
#pragma unroll
    for (int j = 0; j < 4; j++) {
        int col = n0 + j * 16 + l16;
        float bv;
        if (MODE == 4) bv = (col < 512) ? bias[col] : bias2[col - 512];
        else bv = bias[col];
#pragma unroll
        for (int i = 0; i < 2; i++) {
            int rowA = row_base + i * 16;
            if (MODE == 4) {
                if (col < 512) {
                    int hh = col >> 6, d = col & 63;
#pragma unroll
                    for (int r = 0; r < 4; r++) {
                        int row = rowA + r;
                        float v = acc[i][j][r] + bv;
                        ssq[i][r] += v * v;
                        outb[((size_t)((row >> 11) * 8 + hh) * 2048 + (row & 2047)) * 64 + d] = f2bf(v);
                    }
                } else {
                    int c2 = col - 512;
                    int hh = c2 >> 6, d = c2 & 63;
                    int n = rowA & 2047;
                    int a4 = (n >> 2) & 7;
                    int ncol = (n & ~31) + ((a4 & 3) << 3) + ((a4 >> 2) << 2);
                    u32 plo = (u32)f2bf(acc[i][j][0] + bv) | ((u32)f2bf(acc[i][j][1] + bv) << 16);
                    u32 phi = (u32)f2bf(acc[i][j][2] + bv) | ((u32)f2bf(acc[i][j][3] + bv) << 16);
                    uint2 pk; pk.x = plo; pk.y = phi;
                    *(uint2*)&outb2[((size_t)((rowA >> 11) * 8 + hh) * 64 + d) * 2048 + ncol] = pk;
                }
            } else {
#pragma unroll
                for (int r = 0; r < 4; r++) {
                    size_t idx = (size_t)(rowA + r) * N + col;
                    outf[idx] = acc[i][j][r] + bv + res[idx];
                }
            }
        }
    }
    // fused AA for the q-half (block covers exactly one head's 64 d-cols)
    if (MODE == 4 && n0 < 512) {
        int hh = n0 >> 6;
#pragma unroll
        for (int i = 0; i < 2; i++) {
#pragma unroll
            for (int r = 0; r < 4; r++) {
                float s = ssq[i][r];
                s += __shfl_xor(s, 1); s += __shfl_xor(s, 2);
                s += __shfl_xor(s, 4); s += __shfl_xor(s, 8);
                if (l16 == 0) {
                    int row = row_base + i * 16 + r;
                    aa[(size_t)((row >> 11) * 8 + hh) * 2048 + (row & 2047)] = s * 0.125f;
                }
            }
        }
    }
}

// ---------------------------------------------------------------------------
// MFMA flash L2-attention, S^T formulation, j-SPLIT 2-way (flash-decoding).
// Grid 2048: bh = id & 31 (xcd = bh%8 keeps head data in one XCD's L2),
// jsplit = (id>>5)&1, itile = id>>6. Each block does 1024 of the 2048 KV
// positions for its 64 q-rows; writes UNNORMALIZED fp32 O + lr partials
// (safe: sim <= 0 so exp <= 1, lr <= 2048). attn_combine merges.
__global__ __launch_bounds__(256) void attn_mfma(const u16* __restrict__ qbuf,
                                                 const u16* __restrict__ vtp,
                                                 const float* __restrict__ aas,
                                                 float* __restrict__ opart,
                                                 float* __restrict__ lrpart) {
    __shared__ u16 Qj[64][72];
    __shared__ u16 VT[64][72];
    int bid = blockIdx.x;
    int bh = bid & 31;
    int jsplit = (bid >> 5) & 1;
    int itile = bid >> 6;
    int jbase = jsplit << 10;
    const u16* qb = qbuf + (size_t)bh * 2048 * 64;
    const u16* vtb = vtp + (size_t)bh * 64 * 2048;
    const float* aab = aas + (size_t)bh * 2048;
    int t = threadIdx.x;
    int wave = t >> 6, lane = t & 63, quad = lane >> 4, l16 = lane & 15;
    int ibase = itile * 64 + wave * 16;
    bf16x8 qf0 = *(const bf16x8*)(qb + (size_t)(ibase + l16) * 64 + quad * 8);
    bf16x8 qf1 = *(const bf16x8*)(qb + (size_t)(ibase + l16) * 64 + 32 + quad * 8);
    float ci = aab[ibase + l16];
    f32x4 O[4];
#pragma unroll
    for (int nt = 0; nt < 4; nt++) O[nt] = (f32x4){0.f, 0.f, 0.f, 0.f};
    float lr = 0.f;
    int sr = t >> 2, sc = (t & 3) * 16;
    uint4 nq0, nq1, nv0, nv1;
    {
        const u16* srcq = qb + (size_t)(jbase + sr) * 64 + sc;
        nq0 = *(const uint4*)srcq;
        nq1 = *(const uint4*)(srcq + 8);
        const u16* srcv = vtb + (size_t)sr * 2048 + jbase + sc;
        nv0 = *(const uint4*)srcv;
        nv1 = *(const uint4*)(srcv + 8);
    }
    for (int j0 = jbase; j0 < jbase + 1024; j0 += 64) {
        __syncthreads();
        *(uint4*)&Qj[sr][sc] = nq0;
        *(uint4*)&Qj[sr][sc + 8] = nq1;
        *(uint4*)&VT[sr][sc] = nv0;
        *(uint4*)&VT[sr][sc + 8] = nv1;
        if (j0 + 64 < jbase + 1024) {
            const u16* srcq = qb + (size_t)(j0 + 64 + sr) * 64 + sc;
            nq0 = *(const uint4*)srcq;
            nq1 = *(const uint4*)(srcq + 8);
            const u16* srcv = vtb + (size_t)sr * 2048 + (j0 + 64) + sc;
            nv0 = *(const uint4*)srcv;
            nv1 = *(const uint4*)(srcv + 8);
        }
        __syncthreads();
#pragma unroll
        for (int c = 0; c < 2; c++) {
            int j1 = c * 32, j2 = c * 32 + 16;
            bf16x8 a10 = *(const bf16x8*)&Qj[j1 + l16][quad * 8];
            bf16x8 a11 = *(const bf16x8*)&Qj[j1 + l16][32 + quad * 8];
            bf16x8 a20 = *(const bf16x8*)&Qj[j2 + l16][quad * 8];
            bf16x8 a21 = *(const bf16x8*)&Qj[j2 + l16][32 + quad * 8];
            __builtin_amdgcn_s_setprio(1);
            f32x4 s0 = {0.f, 0.f, 0.f, 0.f};
            s0 = __builtin_amdgcn_mfma_f32_16x16x32_bf16(a10, qf0, s0, 0, 0, 0);
            s0 = __builtin_amdgcn_mfma_f32_16x16x32_bf16(a11, qf1, s0, 0, 0, 0);
            f32x4 s1 = {0.f, 0.f, 0.f, 0.f};
            s1 = __builtin_amdgcn_mfma_f32_16x16x32_bf16(a20, qf0, s1, 0, 0, 0);
            s1 = __builtin_amdgcn_mfma_f32_16x16x32_bf16(a21, qf1, s1, 0, 0, 0);
            __builtin_amdgcn_s_setprio(0);
            float4 aav0 = *(const float4*)(aab + j0 + j1 + quad * 4);
            float4 aav1 = *(const float4*)(aab + j0 + j2 + quad * 4);
            float p0 = __expf(s0[0] * 0.25f - aav0.x - ci);
            float p1 = __expf(s0[1] * 0.25f - aav0.y - ci);
            float p2 = __expf(s0[2] * 0.25f - aav0.z - ci);
            float p3 = __expf(s0[3] * 0.25f - aav0.w - ci);
            float p4 = __expf(s1[0] * 0.25f - aav1.x - ci);
            float p5 = __expf(s1[1] * 0.25f - aav1.y - ci);
            float p6 = __expf(s1[2] * 0.25f - aav1.z - ci);
            float p7 = __expf(s1[3] * 0.25f - aav1.w - ci);
            lr += (p0 + p1 + p2 + p3) + (p4 + p5 + p6 + p7);
            bf16x8 pa;
            u32* pu = (u32*)&pa;
            pu[0] = __builtin_amdgcn_perm(__float_as_uint(p1), __float_as_uint(p0), 0x07060302u);
            pu[1] = __builtin_amdgcn_perm(__float_as_uint(p3), __float_as_uint(p2), 0x07060302u);
            pu[2] = __builtin_amdgcn_perm(__float_as_uint(p5), __float_as_uint(p4), 0x07060302u);
            pu[3] = __builtin_amdgcn_perm(__float_as_uint(p7), __float_as_uint(p6), 0x07060302u);
            __builtin_amdgcn_s_setprio(1);
#pragma unroll
            for (int nt = 0; nt < 4; nt++) {
                bf16x8 vf = *(const bf16x8*)&VT[nt * 16 + l16][c * 32 + quad * 8];
                O[nt] = __builtin_amdgcn_mfma_f32_16x16x32_bf16(pa, vf, O[nt], 0, 0, 0);
            }
            __builtin_amdgcn_s_setprio(0);
        }
    }
    lr += __shfl_xor(lr, 16);
    lr += __shfl_xor(lr, 32);
    size_t pslot = (size_t)jsplit * 32 + bh;
    if (lane < 16)
        lrpart[pslot * 2048 + ibase + l16] = lr;
    float* ob = opart + (pslot * 2048 + ibase + quad * 4) * 64 + l16;
#pragma unroll
    for (int r = 0; r < 4; r++) {
        float* o = ob + (size_t)r * 64;
        o[0]  = O[0][r];
        o[16] = O[1][r];
        o[32] = O[2][r];
        o[48] = O[3][r];
    }
}

// ---------------------------------------------------------------------------
// Combine the 2 j-split partials: out = (O0+O1) / (lr0+lr1), bf16.
// Grid 2048 x 256: block covers 32 rows, thread = (row_local = t>>3, 8 d's).
__global__ __launch_bounds__(256) void attn_combine(const float* __restrict__ opart,
                                                    const float* __restrict__ lrpart,
                                                    u16* __restrict__ out) {
    int t = threadIdx.x;
    int rl = t >> 3, d0 = (t & 7) * 8;
    int rg = blockIdx.x * 32 + rl;
    int bh = rg >> 11, i = rg & 2047;
    const float* o0 = opart + ((size_t)bh * 2048 + i) * 64 + d0;
    const float* o1 = o0 + (size_t)32 * 2048 * 64;
    float lr = lrpart[(size_t)bh * 2048 + i] +
               lrpart[(size_t)32 * 2048 + (size_t)bh * 2048 + i];
    float inv = 1.f / lr;
    float4 a0 = *(const float4*)o0;
    float4 a1 = *(const float4*)(o0 + 4);
    float4 b0 = *(const float4*)o1;
    float4 b1 = *(const float4*)(o1 + 4);
    int b = bh >> 3, h = bh & 7;
    u16* op = out + ((size_t)(b * 2048 + i)) * 512 + h * 64 + d0;
    u16 r[8];
    r[0] = f2bf((a0.x + b0.x) * inv);
    r[1] = f2bf((a0.y + b0.y) * inv);
    r[2] = f2bf((a0.z + b0.z) * inv);
    r[3] = f2bf((a0.w + b0.w) * inv);
    r[4] = f2bf((a1.x + b1.x) * inv);
    r[5] = f2bf((a1.y + b1.y) * inv);
    r[6] = f2bf((a1.z + b1.z) * inv);
    r[7] = f2bf((a1.w + b1.w) * inv);
    *(uint4*)op = *(uint4*)r;
}

// ---------------------------------------------------------------------------
extern "C" void kernel_launch(void* const* d_in, const int* in_sizes, int n_in,
                              void* d_out, int out_size, void* d_ws, size_t ws_size,
                              hipStream_t stream) {
    const float* x      = (const float*)d_in[0];
    const float* sa_w   = (const float*)d_in[1];
    const float* sa_b   = (const float*)d_in[2];
    const float* ca_w   = (const float*)d_in[3];
    const float* ca_b   = (const float*)d_in[4];
    const float* ffn_w  = (const float*)d_in[5];
    const float* ffn_b  = (const float*)d_in[6];
    const float* a1_wq  = (const float*)d_in[7];
    const float* a1_bq  = (const float*)d_in[8];
    const float* a1_wv  = (const float*)d_in[9];
    const float* a1_bv  = (const float*)d_in[10];
    const float* a1_wo  = (const float*)d_in[11];
    const float* a1_bo  = (const float*)d_in[12];
    const float* a2_wq  = (const float*)d_in[13];
    const float* a2_bq  = (const float*)d_in[14];
    const float* a2_wv  = (const float*)d_in[15];
    const float* a2_bv  = (const float*)d_in[16];
    const float* a2_wo  = (const float*)d_in[17];
    const float* a2_bo  = (const float*)d_in[18];
    const float* ff_w1  = (const float*)d_in[19];
    const float* ff_b1  = (const float*)d_in[20];
    const float* ff_w2  = (const float*)d_in[21];
    const float* ff_b2  = (const float*)d_in[22];

    char* ws = (char*)d_ws;
    const size_t MB = 1ull << 20;
    float* x_res   = (float*)(ws);              // 16 MB fp32 residual stream
    u16* xn        = (u16*)(ws + 16 * MB);      // 8 MB normed activations (bf16)
    u16* wT_a1qv   = (u16*)(ws + 24 * MB);      // 1 MB [1024][512] (wq^T | wv^T)
    u16* wT_a2qv   = (u16*)(ws + 25 * MB);      // 1 MB
    u16* wT_a1o    = (u16*)(ws + 26 * MB);      // 0.5 MB
    u16* wT_a2o    = (u16*)(ws + 26 * MB + 512 * 1024);
    u16* wT_ff1    = (u16*)(ws + 27 * MB);      // 4 MB [4096][512]
    u16* wT_ff2    = (u16*)(ws + 31 * MB);      // 2 MB [512][2048]
    u16* qbuf      = (u16*)(ws + 34 * MB);      // 8 MB [bh][2048][64]
    u16* vtp       = (u16*)(ws + 42 * MB);      // 8 MB [bh][64][2048] (j-permuted)
    float* aab     = (float*)(ws + 50 * MB);    // 256 KB (0.125*||q||^2)
    float* lrp     = (float*)(ws + 50 * MB + 256 * 1024);  // 512 KB lr partials
    u16* attn_o    = (u16*)(ws + 51 * MB);      // 8 MB bf16 [8192][512]
    u16* gbuf      = (u16*)(ws + 60 * MB);      // 32 MB: FFN gbuf / attn O-partials
    float* opart   = (float*)(ws + 60 * MB);    //   (fp32 [2][32][2048][64], pre-FFN)

    (void)in_sizes; (void)n_in; (void)out_size; (void)ws_size;

    // merged weight transposes (fp32 -> bf16 [N][K]); q|v concatenated
    TArgs ta;
    ta.src[0] = a1_wq; ta.dst[0] = wT_a1qv;               ta.R[0] = 512;  ta.C[0] = 512;
    ta.src[1] = a1_wv; ta.dst[1] = wT_a1qv + 512 * 512;   ta.R[1] = 512;  ta.C[1] = 512;
    ta.src[2] = a2_wq; ta.dst[2] = wT_a2qv;               ta.R[2] = 512;  ta.C[2] = 512;
    ta.src[3] = a2_wv; ta.dst[3] = wT_a2qv + 512 * 512;   ta.R[3] = 512;  ta.C[3] = 512;
    ta.src[4] = a1_wo; ta.dst[4] = wT_a1o;                ta.R[4] = 512;  ta.C[4] = 512;
    ta.src[5] = a2_wo; ta.dst[5] = wT_a2o;                ta.R[5] = 512;  ta.C[5] = 512;
    ta.src[6] = ff_w1; ta.dst[6] = wT_ff1;                ta.R[6] = 512;  ta.C[6] = 4096;
    ta.src[7] = ff_w2; ta.dst[7] = wT_ff2;                ta.R[7] = 2048; ta.C[7] = 512;
    ta.start[0] = 0;
    for (int s = 0; s < 8; s++)
        ta.start[s + 1] = ta.start[s] + (ta.C[s] >> 5) * (ta.R[s] >> 5);
    transpose_multi<<<ta.start[8], 256, 0, stream>>>(ta);

    // === attention 1 (self) ===
    ln_kernel<<<8192, 256, 0, stream>>>(x, sa_w, sa_b, xn);
    gemm_rect<4><<<dim3(64, 16), 256, 0, stream>>>(xn, wT_a1qv, a1_bq, a1_bv, nullptr, nullptr, qbuf, vtp, aab, 8192, 1024, 512);
    attn_mfma<<<2048, 256, 0, stream>>>(qbuf, vtp, aab, opart, lrp);
    attn_combine<<<2048, 256, 0, stream>>>(opart, lrp, attn_o);
    gemm_rect<2><<<dim3(64, 8), 256, 0, stream>>>(attn_o, wT_a1o, a1_bo, nullptr, x, x_res, nullptr, nullptr, nullptr, 8192, 512, 512);

    // === attention 2 ("cross", k=q, v from x) ===
    ln_kernel<<<8192, 256, 0, stream>>>(x_res, ca_w, ca_b, xn);
    gemm_rect<4><<<dim3(64, 16), 256, 0, stream>>>(xn, wT_a2qv, a2_bq, a2_bv, nullptr, nullptr, qbuf, vtp, aab, 8192, 1024, 512);
    attn_mfma<<<2048, 256, 0, stream>>>(qbuf, vtp, aab, opart, lrp);
    attn_combine<<<2048, 256, 0, stream>>>(opart, lrp, attn_o);
    gemm_rect<2><<<dim3(64, 8), 256, 0, stream>>>(attn_o, wT_a2o, a2_bo, nullptr, x_res, x_res, nullptr, nullptr, nullptr, 8192, 512, 512);

    // === GEGLU FFN (geglu fused into ff1; gbuf reuses the O-partial region) ===
    ln_kernel<<<8192, 256, 0, stream>>>(x_res, ffn_w, ffn_b, xn);
    gemm_ff1<<<dim3(64, 32), 256, 0, stream>>>(xn, wT_ff1, ff_b1, gbuf, 512);
    gemm_rect<2><<<dim3(64, 8), 256, 0, stream>>>(gbuf, wT_ff2, ff_b2, nullptr, x_res, (float*)d_out, nullptr, nullptr, nullptr, 8192, 512, 2048);
}

// Round 3
// 384.910 us; speedup vs baseline: 1.1162x; 1.1162x over previous
//
#include <hip/hip_runtime.h>
#include <hip/hip_bf16.h>

// ---------------------------------------------------------------------------
// BasicTransformerBlock (l2-attention x2 + GEGLU FFN), MI355X gfx950
// Round 13: attn_mfma was LDS-throughput-bound (1:1 ds_read:MFMA, ~51us/CU of
// LDS pipe + 8.4M conflict cycles = the whole 69us). Rework:
//   - 2 i-subtiles per wave (32 q-rows/wave, 128-row blocks): each LDS read
//     feeds 2 MFMAs -> LDS traffic per FLOP halved; grid 512 (32bh x 16 itile)
//   - XOR-swizzled unpadded 64x64 LDS tiles (T2): slot ^= (row&7) on 16B units
//   - explicit double-buffer, ONE barrier/iter, prefetch-before-compute (T14)
//   - j-split + combine pass removed (bottleneck was never occupancy/latency)
// ---------------------------------------------------------------------------

typedef short bf16x8 __attribute__((ext_vector_type(8)));
typedef float f32x4 __attribute__((ext_vector_type(4)));
typedef unsigned short u16;
typedef unsigned int u32;

__device__ __forceinline__ float bf2f(u16 u) {
    return __uint_as_float(((u32)u) << 16);
}
__device__ __forceinline__ u16 f2bf(float f) {
    u32 u = __float_as_uint(f);
    u32 rb = ((u >> 16) & 1u) + 0x7fffu;   // round-to-nearest-even
    return (u16)((u + rb) >> 16);
}
// tanh-form gelu: x * sigmoid(1.59577(x + 0.044715 x^3)); |err| <~1e-3.
__device__ __forceinline__ float gelu_fast(float x) {
    float y = 1.5957691216f * (x + 0.044715f * x * x * x);
    return x / (1.f + __expf(-y));
}
__device__ __forceinline__ void gl2lds16(const u16* g, u16* l) {
    __builtin_amdgcn_global_load_lds(
        (const __attribute__((address_space(1))) void*)(unsigned long long)(uintptr_t)g,
        (__attribute__((address_space(3))) void*)(unsigned long long)(uintptr_t)l,
        16, 0, 0);
}

// ---------------------------------------------------------------------------
// Merged weight transpose: 8 segments of fp32 [R][C] -> bf16 [C][R].
struct TArgs {
    const float* src[8];
    u16* dst[8];
    int R[8], C[8];
    int start[9];
};
__global__ __launch_bounds__(256) void transpose_multi(TArgs a) {
    __shared__ float tile[32][33];
    int bid = blockIdx.x;
    int s = 0;
    while (bid >= a.start[s + 1]) s++;
    int local = bid - a.start[s];
    int R = a.R[s], C = a.C[s];
    int tx = C >> 5;
    int bx = local % tx, by = local / tx;
    const float* in = a.src[s];
    u16* out = a.dst[s];
    int t = threadIdx.x;
    int c = t & 31, r0 = (t >> 5) * 4;
#pragma unroll
    for (int i = 0; i < 4; i++)
        tile[r0 + i][c] = in[(size_t)(by * 32 + r0 + i) * C + bx * 32 + c];
    __syncthreads();
#pragma unroll
    for (int i = 0; i < 4; i++)
        out[(size_t)(bx * 32 + r0 + i) * R + by * 32 + c] = f2bf(tile[c][r0 + i]);
}

// ---------------------------------------------------------------------------
// LayerNorm: x fp32 [rows][512] -> out bf16, one block per row
__global__ __launch_bounds__(256) void ln_kernel(const float* __restrict__ x,
                                                 const float* __restrict__ w,
                                                 const float* __restrict__ b,
                                                 u16* __restrict__ out) {
    int row = blockIdx.x, t = threadIdx.x;
    const float* xr = x + (size_t)row * 512;
    float2 v = *(const float2*)(xr + t * 2);
    float s1 = v.x + v.y;
    float s2 = v.x * v.x + v.y * v.y;
#pragma unroll
    for (int m = 1; m < 64; m <<= 1) {
        s1 += __shfl_xor(s1, m);
        s2 += __shfl_xor(s2, m);
    }
    __shared__ float r1[4], r2[4];
    int wave = t >> 6, lane = t & 63;
    if (lane == 0) { r1[wave] = s1; r2[wave] = s2; }
    __syncthreads();
    float tot1 = r1[0] + r1[1] + r1[2] + r1[3];
    float tot2 = r2[0] + r2[1] + r2[2] + r2[3];
    float mu = tot1 * (1.f / 512.f);
    float var = tot2 * (1.f / 512.f) - mu * mu;
    float rs = rsqrtf(var + 1e-5f);
    float2 wv = *(const float2*)(w + t * 2);
    float2 bv = *(const float2*)(b + t * 2);
    float o0 = (v.x - mu) * rs * wv.x + bv.x;
    float o1 = (v.y - mu) * rs * wv.y + bv.y;
    u32 pack = (u32)f2bf(o0) | ((u32)f2bf(o1) << 16);
    *(u32*)(out + (size_t)row * 512 + t * 2) = pack;
}

// ---------------------------------------------------------------------------
// ff1+GEGLU fused rect GEMM: A [8192][512] bf16, BT = ff1^T [4096][512].
// Epilogue: g = a * gelu(gate) -> gbuf [8192][2048] bf16.
__global__ __launch_bounds__(256) void gemm_ff1(const u16* __restrict__ A,
                                                const u16* __restrict__ BT,
                                                const float* __restrict__ bias,
                                                u16* __restrict__ gout,
                                                int K) {
    __shared__ u16 As[2][128 * 32];
    __shared__ u16 Bs[2][128 * 32];   // rows 0-63 = a-half, 64-127 = gate-half
    int t = threadIdx.x;
    int wave = t >> 6, lane = t & 63, quad = lane >> 4, l16 = lane & 15;
    int m0 = blockIdx.x * 128, n0 = blockIdx.y * 64;
    f32x4 aacc[2][4], gacc[2][4];
#pragma unroll
    for (int i = 0; i < 2; i++)
#pragma unroll
        for (int j = 0; j < 4; j++) {
            aacc[i][j] = (f32x4){0.f, 0.f, 0.f, 0.f};
            gacc[i][j] = (f32x4){0.f, 0.f, 0.f, 0.f};
        }
    const u16* Ag = A + (size_t)(m0 + wave * 32 + (lane >> 2)) * K + (lane & 3) * 8;
    int brow = (wave < 2) ? (n0 + wave * 32) : (2048 + n0 + (wave - 2) * 32);
    const u16* Bg = BT + (size_t)(brow + (lane >> 2)) * K + (lane & 3) * 8;
    int lo = wave * 32 * 32;
    const size_t rstep = (size_t)16 * K;
    gl2lds16(Ag, &As[0][lo]);
    gl2lds16(Ag + rstep, &As[0][lo + 16 * 32]);
    gl2lds16(Bg, &Bs[0][lo]);
    gl2lds16(Bg + rstep, &Bs[0][lo + 16 * 32]);
    int buf = 0;
    for (int k0 = 0; k0 < K; k0 += 32, buf ^= 1) {
        int kn = (k0 + 32 < K) ? (k0 + 32) : k0;
        int nb = buf ^ 1;
        asm volatile("s_waitcnt lgkmcnt(0)\n\ts_barrier" ::: "memory");
        gl2lds16(Ag + kn, &As[nb][lo]);
        gl2lds16(Ag + kn + rstep, &As[nb][lo + 16 * 32]);
        gl2lds16(Bg + kn, &Bs[nb][lo]);
        gl2lds16(Bg + kn + rstep, &Bs[nb][lo + 16 * 32]);
        asm volatile("s_waitcnt vmcnt(4)\n\ts_barrier" ::: "memory");
        bf16x8 a[2];
#pragma unroll
        for (int i = 0; i < 2; i++)
            a[i] = *(const bf16x8*)&As[buf][(wave * 32 + i * 16 + l16) * 32 + quad * 8];
#pragma unroll
        for (int j = 0; j < 4; j++) {
            bf16x8 ba = *(const bf16x8*)&Bs[buf][(j * 16 + l16) * 32 + quad * 8];
            bf16x8 bg = *(const bf16x8*)&Bs[buf][(64 + j * 16 + l16) * 32 + quad * 8];
#pragma unroll
            for (int i = 0; i < 2; i++) {
                aacc[i][j] = __builtin_amdgcn_mfma_f32_16x16x32_bf16(a[i], ba, aacc[i][j], 0, 0, 0);
                gacc[i][j] = __builtin_amdgcn_mfma_f32_16x16x32_bf16(a[i], bg, gacc[i][j], 0, 0, 0);
            }
        }
    }
    asm volatile("s_waitcnt vmcnt(0)" ::: "memory");   // drain DMA before endpgm
    int row_base = m0 + wave * 32 + quad * 4;
#pragma unroll
    for (int j = 0; j < 4; j++) {
        int col = n0 + j * 16 + l16;
        float ba = bias[col];
        float bg = bias[2048 + col];
#pragma unroll
        for (int i = 0; i < 2; i++) {
#pragma unroll
            for (int r = 0; r < 4; r++) {
                int row = row_base + i * 16 + r;
                float av = aacc[i][j][r] + ba;
                float gv = gacc[i][j][r] + bg;
                gout[(size_t)row * 2048 + col] = f2bf(av * gelu_fast(gv));
            }
        }
    }
}

// ---------------------------------------------------------------------------
// Rect 128x64 MFMA GEMM (double-buffered, vmcnt(3)).
// MODE 2: fp32 out = acc + res | 4: qv split:
//   col<512 (q): qbuf [(b*8+h)][n][64] + fused AA write (aa = 0.125*sum q^2)
//   col>=512 (v): vtp [(b*8+h)][64][2048] j-cols PERMUTED per aligned 32-block
template <int MODE>
__global__ __launch_bounds__(256) void gemm_rect(const u16* __restrict__ A,
                                                 const u16* __restrict__ BT,
                                                 const float* __restrict__ bias,
                                                 const float* __restrict__ bias2,
                                                 const float* __restrict__ res,
                                                 float* __restrict__ outf,
                                                 u16* __restrict__ outb,
                                                 u16* __restrict__ outb2,
                                                 float* __restrict__ aa,
                                                 int M, int N, int K) {
    __shared__ u16 As[2][128 * 32];
    __shared__ u16 Bs[2][64 * 32];
    int t = threadIdx.x;
    int wave = t >> 6, lane = t & 63, quad = lane >> 4, l16 = lane & 15;
    int m0 = blockIdx.x * 128, n0 = blockIdx.y * 64;
    f32x4 acc[2][4];
#pragma unroll
    for (int i = 0; i < 2; i++)
#pragma unroll
        for (int j = 0; j < 4; j++) acc[i][j] = (f32x4){0.f, 0.f, 0.f, 0.f};
    const u16* Ag = A + (size_t)(m0 + wave * 32 + (lane >> 2)) * K + (lane & 3) * 8;
    const u16* Bg = BT + (size_t)(n0 + wave * 16 + (lane >> 2)) * K + (lane & 3) * 8;
    int loA = wave * 32 * 32;
    int loB = wave * 16 * 32;
    const size_t rstep = (size_t)16 * K;
    gl2lds16(Ag, &As[0][loA]);
    gl2lds16(Ag + rstep, &As[0][loA + 16 * 32]);
    gl2lds16(Bg, &Bs[0][loB]);
    int buf = 0;
    for (int k0 = 0; k0 < K; k0 += 32, buf ^= 1) {
        int kn = (k0 + 32 < K) ? (k0 + 32) : k0;
        int nb = buf ^ 1;
        asm volatile("s_waitcnt lgkmcnt(0)\n\ts_barrier" ::: "memory");
        gl2lds16(Ag + kn, &As[nb][loA]);
        gl2lds16(Ag + kn + rstep, &As[nb][loA + 16 * 32]);
        gl2lds16(Bg + kn, &Bs[nb][loB]);
        asm volatile("s_waitcnt vmcnt(3)\n\ts_barrier" ::: "memory");
        bf16x8 a[2], b[4];
#pragma unroll
        for (int i = 0; i < 2; i++)
            a[i] = *(const bf16x8*)&As[buf][(wave * 32 + i * 16 + l16) * 32 + quad * 8];
#pragma unroll
        for (int j = 0; j < 4; j++)
            b[j] = *(const bf16x8*)&Bs[buf][(j * 16 + l16) * 32 + quad * 8];
#pragma unroll
        for (int i = 0; i < 2; i++)
#pragma unroll
            for (int j = 0; j < 4; j++)
                acc[i][j] = __builtin_amdgcn_mfma_f32_16x16x32_bf16(a[i], b[j], acc[i][j], 0, 0, 0);
    }
    asm volatile("s_waitcnt vmcnt(0)" ::: "memory");   // drain DMA before endpgm
    int row_base = m0 + wave * 32 + quad * 4;
    float ssq[2][4];
#pragma unroll
    for (int i = 0; i < 2; i++)
#pragma unroll
        for (int r = 0; r < 4; r++) ssq[i][r] = 0.f;
#pragma unroll
    for (int j = 0; j < 4; j++) {
        int col = n0 + j * 16 + l16;
        float bv;
        if (MODE == 4) bv = (col < 512) ? bias[col] : bias2[col - 512];
        else bv = bias[col];
#pragma unroll
        for (int i = 0; i < 2; i++) {
            int rowA = row_base + i * 16;
            if (MODE == 4) {
                if (col < 512) {
                    int hh = col >> 6, d = col & 63;
#pragma unroll
                    for (int r = 0; r < 4; r++) {
                        int row = rowA + r;
                        float v = acc[i][j][r] + bv;
                        ssq[i][r] += v * v;
                        outb[((size_t)((row >> 11) * 8 + hh) * 2048 + (row & 2047)) * 64 + d] = f2bf(v);
                    }
                } else {
                    int c2 = col - 512;
                    int hh = c2 >> 6, d = c2 & 63;
                    int n = rowA & 2047;
                    int a4 = (n >> 2) & 7;
                    int ncol = (n & ~31) + ((a4 & 3) << 3) + ((a4 >> 2) << 2);
                    u32 plo = (u32)f2bf(acc[i][j][0] + bv) | ((u32)f2bf(acc[i][j][1] + bv) << 16);
                    u32 phi = (u32)f2bf(acc[i][j][2] + bv) | ((u32)f2bf(acc[i][j][3] + bv) << 16);
                    uint2 pk; pk.x = plo; pk.y = phi;
                    *(uint2*)&outb2[((size_t)((rowA >> 11) * 8 + hh) * 64 + d) * 2048 + ncol] = pk;
                }
            } else {
#pragma unroll
                for (int r = 0; r < 4; r++) {
                    size_t idx = (size_t)(rowA + r) * N + col;
                    outf[idx] = acc[i][j][r] + bv + res[idx];
                }
            }
        }
    }
    // fused AA for the q-half (block covers exactly one head's 64 d-cols)
    if (MODE == 4 && n0 < 512) {
        int hh = n0 >> 6;
#pragma unroll
        for (int i = 0; i < 2; i++) {
#pragma unroll
            for (int r = 0; r < 4; r++) {
                float s = ssq[i][r];
                s += __shfl_xor(s, 1); s += __shfl_xor(s, 2);
                s += __shfl_xor(s, 4); s += __shfl_xor(s, 8);
                if (l16 == 0) {
                    int row = row_base + i * 16 + r;
                    aa[(size_t)((row >> 11) * 8 + hh) * 2048 + (row & 2047)] = s * 0.125f;
                }
            }
        }
    }
}

// ---------------------------------------------------------------------------
// MFMA flash L2-attention, S^T formulation, 2 i-subtiles/wave, swizzled LDS.
// Grid 512: bh = bid & 31 (xcd = bh%8 keeps head q/vt in one XCD's L2),
// itile = bid >> 5 (16 x 128 q-rows). Each wave owns 32 q-rows (2 subtiles),
// so every LDS a/b-frag read feeds 2 MFMAs (was 1). LDS tiles 64x64 u16,
// XOR-swizzled on 16B slots: phys_slot = slot ^ (row & 7). Double-buffered,
// one barrier/iter, global prefetch issued before compute.
__global__ __launch_bounds__(256) void attn_mfma(const u16* __restrict__ qbuf,
                                                 const u16* __restrict__ vtp,
                                                 const float* __restrict__ aas,
                                                 u16* __restrict__ out) {
    __shared__ u16 L[2][8192];   // per buf: [0..4095]=Qj (64x64 swz), [4096..]=VT
    int bid = blockIdx.x;
    int bh = bid & 31;
    int itile = bid >> 5;
    const u16* qb = qbuf + (size_t)bh * 2048 * 64;
    const u16* vtb = vtp + (size_t)bh * 64 * 2048;
    const float* aab = aas + (size_t)bh * 2048;
    int t = threadIdx.x;
    int wave = t >> 6, lane = t & 63, quad = lane >> 4, l16 = lane & 15;
    int ibase = itile * 128 + wave * 32;
    int sw = l16 & 7;

    bf16x8 qf[2][2];
    float ci[2];
    f32x4 O[2][4];
    float lr[2] = {0.f, 0.f};
#pragma unroll
    for (int st = 0; st < 2; st++) {
        const u16* qr = qb + (size_t)(ibase + st * 16 + l16) * 64;
        qf[st][0] = *(const bf16x8*)(qr + quad * 8);
        qf[st][1] = *(const bf16x8*)(qr + 32 + quad * 8);
        ci[st] = aab[ibase + st * 16 + l16];
#pragma unroll
        for (int nt = 0; nt < 4; nt++) O[st][nt] = (f32x4){0.f, 0.f, 0.f, 0.f};
    }

    // staging: thread covers Q rows {r1, r1+32} and V rows {r1, r1+32},
    // 16B (8 u16) each at column-slot cs; LDS write offset XOR-swizzled.
    int r1 = t >> 3, cs = t & 7;
    int wof1 = r1 * 64 + 8 * (cs ^ (r1 & 7));
    int wof2 = (r1 + 32) * 64 + 8 * (cs ^ (r1 & 7));

    // prologue: tile j0 = 0 into buf 0
    {
        uint4 pq1 = *(const uint4*)(qb + (size_t)r1 * 64 + cs * 8);
        uint4 pq2 = *(const uint4*)(qb + (size_t)(r1 + 32) * 64 + cs * 8);
        uint4 pv1 = *(const uint4*)(vtb + (size_t)r1 * 2048 + cs * 8);
        uint4 pv2 = *(const uint4*)(vtb + (size_t)(r1 + 32) * 2048 + cs * 8);
        *(uint4*)&L[0][wof1] = pq1;
        *(uint4*)&L[0][wof2] = pq2;
        *(uint4*)&L[0][4096 + wof1] = pv1;
        *(uint4*)&L[0][4096 + wof2] = pv2;
    }
    __syncthreads();

    for (int it = 0; it < 32; ++it) {
        int cur = it & 1;
        int j0 = it << 6;
        uint4 pq1, pq2, pv1, pv2;
        bool more = (it + 1 < 32);
        if (more) {
            int j0n = j0 + 64;
            pq1 = *(const uint4*)(qb + (size_t)(j0n + r1) * 64 + cs * 8);
            pq2 = *(const uint4*)(qb + (size_t)(j0n + r1 + 32) * 64 + cs * 8);
            pv1 = *(const uint4*)(vtb + (size_t)r1 * 2048 + j0n + cs * 8);
            pv2 = *(const uint4*)(vtb + (size_t)(r1 + 32) * 2048 + j0n + cs * 8);
        }
        const u16* Q = &L[cur][0];
        const u16* V = &L[cur][4096];
#pragma unroll
        for (int c = 0; c < 2; c++) {
            int r10 = c * 32 + l16, r20 = c * 32 + 16 + l16;
            bf16x8 a10 = *(const bf16x8*)&Q[r10 * 64 + 8 * (quad ^ sw)];
            bf16x8 a11 = *(const bf16x8*)&Q[r10 * 64 + 8 * ((4 + quad) ^ sw)];
            bf16x8 a20 = *(const bf16x8*)&Q[r20 * 64 + 8 * (quad ^ sw)];
            bf16x8 a21 = *(const bf16x8*)&Q[r20 * 64 + 8 * ((4 + quad) ^ sw)];
            f32x4 s0[2], s1[2];
            __builtin_amdgcn_s_setprio(1);
#pragma unroll
            for (int st = 0; st < 2; st++) {
                f32x4 z = {0.f, 0.f, 0.f, 0.f};
                s0[st] = __builtin_amdgcn_mfma_f32_16x16x32_bf16(a10, qf[st][0], z, 0, 0, 0);
                s0[st] = __builtin_amdgcn_mfma_f32_16x16x32_bf16(a11, qf[st][1], s0[st], 0, 0, 0);
                s1[st] = __builtin_amdgcn_mfma_f32_16x16x32_bf16(a20, qf[st][0], z, 0, 0, 0);
                s1[st] = __builtin_amdgcn_mfma_f32_16x16x32_bf16(a21, qf[st][1], s1[st], 0, 0, 0);
            }
            __builtin_amdgcn_s_setprio(0);
            float4 aav0 = *(const float4*)(aab + j0 + c * 32 + quad * 4);
            float4 aav1 = *(const float4*)(aab + j0 + c * 32 + 16 + quad * 4);
            bf16x8 pa[2];
#pragma unroll
            for (int st = 0; st < 2; st++) {
                float p0 = __expf(s0[st][0] * 0.25f - aav0.x - ci[st]);
                float p1 = __expf(s0[st][1] * 0.25f - aav0.y - ci[st]);
                float p2 = __expf(s0[st][2] * 0.25f - aav0.z - ci[st]);
                float p3 = __expf(s0[st][3] * 0.25f - aav0.w - ci[st]);
                float p4 = __expf(s1[st][0] * 0.25f - aav1.x - ci[st]);
                float p5 = __expf(s1[st][1] * 0.25f - aav1.y - ci[st]);
                float p6 = __expf(s1[st][2] * 0.25f - aav1.z - ci[st]);
                float p7 = __expf(s1[st][3] * 0.25f - aav1.w - ci[st]);
                lr[st] += (p0 + p1 + p2 + p3) + (p4 + p5 + p6 + p7);
                u32* pu = (u32*)&pa[st];
                pu[0] = __builtin_amdgcn_perm(__float_as_uint(p1), __float_as_uint(p0), 0x07060302u);
                pu[1] = __builtin_amdgcn_perm(__float_as_uint(p3), __float_as_uint(p2), 0x07060302u);
                pu[2] = __builtin_amdgcn_perm(__float_as_uint(p5), __float_as_uint(p4), 0x07060302u);
                pu[3] = __builtin_amdgcn_perm(__float_as_uint(p7), __float_as_uint(p6), 0x07060302u);
            }
            __builtin_amdgcn_s_setprio(1);
#pragma unroll
            for (int nt = 0; nt < 4; nt++) {
                int rv = nt * 16 + l16;
                bf16x8 vf = *(const bf16x8*)&V[rv * 64 + 8 * ((c * 4 + quad) ^ sw)];
                O[0][nt] = __builtin_amdgcn_mfma_f32_16x16x32_bf16(pa[0], vf, O[0][nt], 0, 0, 0);
                O[1][nt] = __builtin_amdgcn_mfma_f32_16x16x32_bf16(pa[1], vf, O[1][nt], 0, 0, 0);
            }
            __builtin_amdgcn_s_setprio(0);
        }
        if (more) {
            u16* D = &L[cur ^ 1][0];
            *(uint4*)&D[wof1] = pq1;
            *(uint4*)&D[wof2] = pq2;
            *(uint4*)&D[4096 + wof1] = pv1;
            *(uint4*)&D[4096 + wof2] = pv2;
        }
        __syncthreads();
    }

    int b = bh >> 3, h = bh & 7;
#pragma unroll
    for (int st = 0; st < 2; st++) {
        float l = lr[st];
        l += __shfl_xor(l, 16);
        l += __shfl_xor(l, 32);
        float inv = 1.f / l;
#pragma unroll
        for (int r = 0; r < 4; r++) {
            float invr = __shfl(inv, quad * 4 + r);
            size_t row = (size_t)(b * 2048 + ibase + st * 16 + quad * 4 + r);
            u16* o = out + row * 512 + h * 64 + l16;
            o[0]  = f2bf(O[st][0][r] * invr);
            o[16] = f2bf(O[st][1][r] * invr);
            o[32] = f2bf(O[st][2][r] * invr);
            o[48] = f2bf(O[st][3][r] * invr);
        }
    }
}

// ---------------------------------------------------------------------------
extern "C" void kernel_launch(void* const* d_in, const int* in_sizes, int n_in,
                              void* d_out, int out_size, void* d_ws, size_t ws_size,
                              hipStream_t stream) {
    const float* x      = (const float*)d_in[0];
    const float* sa_w   = (const float*)d_in[1];
    const float* sa_b   = (const float*)d_in[2];
    const float* ca_w   = (const float*)d_in[3];
    const float* ca_b   = (const float*)d_in[4];
    const float* ffn_w  = (const float*)d_in[5];
    const float* ffn_b  = (const float*)d_in[6];
    const float* a1_wq  = (const float*)d_in[7];
    const float* a1_bq  = (const float*)d_in[8];
    const float* a1_wv  = (const float*)d_in[9];
    const float* a1_bv  = (const float*)d_in[10];
    const float* a1_wo  = (const float*)d_in[11];
    const float* a1_bo  = (const float*)d_in[12];
    const float* a2_wq  = (const float*)d_in[13];
    const float* a2_bq  = (const float*)d_in[14];
    const float* a2_wv  = (const float*)d_in[15];
    const float* a2_bv  = (const float*)d_in[16];
    const float* a2_wo  = (const float*)d_in[17];
    const float* a2_bo  = (const float*)d_in[18];
    const float* ff_w1  = (const float*)d_in[19];
    const float* ff_b1  = (const float*)d_in[20];
    const float* ff_w2  = (const float*)d_in[21];
    const float* ff_b2  = (const float*)d_in[22];

    char* ws = (char*)d_ws;
    const size_t MB = 1ull << 20;
    float* x_res   = (float*)(ws);              // 16 MB fp32 residual stream
    u16* xn        = (u16*)(ws + 16 * MB);      // 8 MB normed activations (bf16)
    u16* wT_a1qv   = (u16*)(ws + 24 * MB);      // 1 MB [1024][512] (wq^T | wv^T)
    u16* wT_a2qv   = (u16*)(ws + 25 * MB);      // 1 MB
    u16* wT_a1o    = (u16*)(ws + 26 * MB);      // 0.5 MB
    u16* wT_a2o    = (u16*)(ws + 26 * MB + 512 * 1024);
    u16* wT_ff1    = (u16*)(ws + 27 * MB);      // 4 MB [4096][512]
    u16* wT_ff2    = (u16*)(ws + 31 * MB);      // 2 MB [512][2048]
    u16* qbuf      = (u16*)(ws + 34 * MB);      // 8 MB [bh][2048][64]
    u16* vtp       = (u16*)(ws + 42 * MB);      // 8 MB [bh][64][2048] (j-permuted)
    float* aab     = (float*)(ws + 50 * MB);    // 256 KB (0.125*||q||^2)
    u16* attn_o    = (u16*)(ws + 51 * MB);      // 8 MB bf16 [8192][512]
    u16* gbuf      = (u16*)(ws + 60 * MB);      // 32 MB [8192][2048] bf16

    (void)in_sizes; (void)n_in; (void)out_size; (void)ws_size;

    // merged weight transposes (fp32 -> bf16 [N][K]); q|v concatenated
    TArgs ta;
    ta.src[0] = a1_wq; ta.dst[0] = wT_a1qv;               ta.R[0] = 512;  ta.C[0] = 512;
    ta.src[1] = a1_wv; ta.dst[1] = wT_a1qv + 512 * 512;   ta.R[1] = 512;  ta.C[1] = 512;
    ta.src[2] = a2_wq; ta.dst[2] = wT_a2qv;               ta.R[2] = 512;  ta.C[2] = 512;
    ta.src[3] = a2_wv; ta.dst[3] = wT_a2qv + 512 * 512;   ta.R[3] = 512;  ta.C[3] = 512;
    ta.src[4] = a1_wo; ta.dst[4] = wT_a1o;                ta.R[4] = 512;  ta.C[4] = 512;
    ta.src[5] = a2_wo; ta.dst[5] = wT_a2o;                ta.R[5] = 512;  ta.C[5] = 512;
    ta.src[6] = ff_w1; ta.dst[6] = wT_ff1;                ta.R[6] = 512;  ta.C[6] = 4096;
    ta.src[7] = ff_w2; ta.dst[7] = wT_ff2;                ta.R[7] = 2048; ta.C[7] = 512;
    ta.start[0] = 0;
    for (int s = 0; s < 8; s++)
        ta.start[s + 1] = ta.start[s] + (ta.C[s] >> 5) * (ta.R[s] >> 5);
    transpose_multi<<<ta.start[8], 256, 0, stream>>>(ta);

    // === attention 1 (self) ===
    ln_kernel<<<8192, 256, 0, stream>>>(x, sa_w, sa_b, xn);
    gemm_rect<4><<<dim3(64, 16), 256, 0, stream>>>(xn, wT_a1qv, a1_bq, a1_bv, nullptr, nullptr, qbuf, vtp, aab, 8192, 1024, 512);
    attn_mfma<<<512, 256, 0, stream>>>(qbuf, vtp, aab, attn_o);
    gemm_rect<2><<<dim3(64, 8), 256, 0, stream>>>(attn_o, wT_a1o, a1_bo, nullptr, x, x_res, nullptr, nullptr, nullptr, 8192, 512, 512);

    // === attention 2 ("cross", k=q, v from x) ===
    ln_kernel<<<8192, 256, 0, stream>>>(x_res, ca_w, ca_b, xn);
    gemm_rect<4><<<dim3(64, 16), 256, 0, stream>>>(xn, wT_a2qv, a2_bq, a2_bv, nullptr, nullptr, qbuf, vtp, aab, 8192, 1024, 512);
    attn_mfma<<<512, 256, 0, stream>>>(qbuf, vtp, aab, attn_o);
    gemm_rect<2><<<dim3(64, 8), 256, 0, stream>>>(attn_o, wT_a2o, a2_bo, nullptr, x_res, x_res, nullptr, nullptr, nullptr, 8192, 512, 512);

    // === GEGLU FFN (geglu fused into ff1) ===
    ln_kernel<<<8192, 256, 0, stream>>>(x_res, ffn_w, ffn_b, xn);
    gemm_ff1<<<dim3(64, 32), 256, 0, stream>>>(xn, wT_ff1, ff_b1, gbuf, 512);
    gemm_rect<2><<<dim3(64, 8), 256, 0, stream>>>(gbuf, wT_ff2, ff_b2, nullptr, x_res, (float*)d_out, nullptr, nullptr, nullptr, 8192, 512, 2048);
}